// Round 1
// baseline (193.905 us; speedup 1.0000x reference)
//
#include <hip/hip_runtime.h>

#define N_NODES 16384
#define N_EDGES 65536

// h1[n,o] = bias1[o] + sum_{i<8} x[n,i] * root1[i,o]
__global__ void k_node1(const float* __restrict__ x, const float* __restrict__ root1,
                        const float* __restrict__ bias1, float* __restrict__ h1) {
    int t = blockIdx.x * blockDim.x + threadIdx.x;   // t in [0, N*64)
    int n = t >> 6, o = t & 63;
    float acc = bias1[o];
#pragma unroll
    for (int i = 0; i < 8; ++i)
        acc = fmaf(x[n * 8 + i], root1[i * 64 + o], acc);
    h1[t] = acc;
}

// layer-1 edge kernel: wave per edge, weights (8 x 3 floats per lane) in registers
__global__ __launch_bounds__(64, 4)
void k_edge1(const float* __restrict__ x, const int* __restrict__ ei,
             const float* __restrict__ ea, const float* __restrict__ A1,
             const float* __restrict__ b1, float* __restrict__ h1) {
    int lane = threadIdx.x;
    float w0[8], w1[8], bb[8];
#pragma unroll
    for (int i = 0; i < 8; ++i) {
        w0[i] = A1[i * 64 + lane];
        w1[i] = A1[512 + i * 64 + lane];
        bb[i] = b1[i * 64 + lane];
    }
    for (int e = blockIdx.x; e < N_EDGES; e += gridDim.x) {
        int src = ei[e];
        int dst = ei[N_EDGES + e];
        float ea0 = ea[e * 2], ea1 = ea[e * 2 + 1];
        float xr = x[src * 8 + (lane & 7)];   // lanes 0..7 hold the x row (replicated)
        float acc = 0.f;
#pragma unroll
        for (int i = 0; i < 8; ++i) {
            float h = __shfl(xr, i);
            float wv = fmaf(ea1, w1[i], fmaf(ea0, w0[i], bb[i]));
            wv = fmaxf(wv, 0.f);
            acc = fmaf(h, wv, acc);
        }
        atomicAdd(&h1[dst * 64 + lane], acc);
    }
}

// out[n,o] = bias2[o] + sum_{i<64} h1[n,i] * root2[i,o]
__global__ void k_node2(const float* __restrict__ h1, const float* __restrict__ root2,
                        const float* __restrict__ bias2, float* __restrict__ out) {
    int t = blockIdx.x * blockDim.x + threadIdx.x;
    int o = t & 63;
    float hr = h1[t];                 // each wave covers exactly one node row
    float acc = bias2[o];
#pragma unroll
    for (int i = 0; i < 64; ++i)
        acc = fmaf(__shfl(hr, i), root2[i * 64 + o], acc);
    out[t] = acc;
}

// layer-2 edge kernel: wave per edge, weights (64 x 3 floats per lane) in registers
__global__ __launch_bounds__(64, 2)
void k_edge2(const float* __restrict__ h1, const int* __restrict__ ei,
             const float* __restrict__ ea, const float* __restrict__ A2,
             const float* __restrict__ b2, float* __restrict__ out) {
    int lane = threadIdx.x;
    float w0[64], w1[64], bb[64];
#pragma unroll
    for (int i = 0; i < 64; ++i) {
        w0[i] = A2[i * 64 + lane];
        w1[i] = A2[4096 + i * 64 + lane];
        bb[i] = b2[i * 64 + lane];
    }
    for (int e = blockIdx.x; e < N_EDGES; e += gridDim.x) {
        int src = ei[e];
        int dst = ei[N_EDGES + e];
        float ea0 = ea[e * 2], ea1 = ea[e * 2 + 1];
        float hr = h1[src * 64 + lane];   // coalesced row load, lane o holds h[src,o]
        float acc = 0.f;
#pragma unroll
        for (int i = 0; i < 64; ++i) {
            float h = __shfl(hr, i);
            float wv = fmaf(ea1, w1[i], fmaf(ea0, w0[i], bb[i]));
            wv = fmaxf(wv, 0.f);
            acc = fmaf(h, wv, acc);
        }
        atomicAdd(&out[dst * 64 + lane], acc);
    }
}

extern "C" void kernel_launch(void* const* d_in, const int* in_sizes, int n_in,
                              void* d_out, int out_size, void* d_ws, size_t ws_size,
                              hipStream_t stream) {
    const float* x     = (const float*)d_in[0];
    const int*   ei    = (const int*)d_in[1];
    const float* ea    = (const float*)d_in[2];
    const float* A1    = (const float*)d_in[3];
    const float* b1    = (const float*)d_in[4];
    const float* A2    = (const float*)d_in[5];
    const float* b2    = (const float*)d_in[6];
    const float* root1 = (const float*)d_in[7];
    const float* bias1 = (const float*)d_in[8];
    const float* root2 = (const float*)d_in[9];
    const float* bias2 = (const float*)d_in[10];
    float* out = (float*)d_out;
    float* h1  = (float*)d_ws;        // N*64 floats = 4 MB scratch

    // 1) h1 = bias1 + x @ root1   (fully initializes ws accumulator)
    k_node1<<<N_NODES * 64 / 256, 256, 0, stream>>>(x, root1, bias1, h1);
    // 2) h1 += scatter-add of layer-1 edge messages
    k_edge1<<<2048, 64, 0, stream>>>(x, ei, ea, A1, b1, h1);
    // 3) out = bias2 + h1 @ root2 (fully initializes d_out)
    k_node2<<<N_NODES * 64 / 256, 256, 0, stream>>>(h1, root2, bias2, out);
    // 4) out += scatter-add of layer-2 edge messages
    k_edge2<<<2048, 64, 0, stream>>>(h1, ei, ea, A2, b2, out);
}

// Round 5
// 147.502 us; speedup vs baseline: 1.3146x; 1.3146x over previous
//
#include <hip/hip_runtime.h>

#define N_NODES 16384
#define N_EDGES 65536

typedef float f32x16 __attribute__((ext_vector_type(16)));
typedef float f32x8  __attribute__((ext_vector_type(8)));

__device__ __forceinline__ float rfl_f(float v) {
    int i = __builtin_amdgcn_readfirstlane(__builtin_bit_cast(int, v));
    return __builtin_bit_cast(float, i);
}

// h1[n,o] = bias1[o] + sum_{i<8} x[n,i] * root1[i,o]
__global__ void k_node1(const float* __restrict__ x, const float* __restrict__ root1,
                        const float* __restrict__ bias1, float* __restrict__ h1) {
    int t = blockIdx.x * blockDim.x + threadIdx.x;   // t in [0, N*64)
    int n = t >> 6, o = t & 63;
    float acc = bias1[o];
#pragma unroll
    for (int i = 0; i < 8; ++i)
        acc = fmaf(x[n * 8 + i], root1[i * 64 + o], acc);
    h1[t] = acc;
}

// layer-1 edge kernel: wave per edge; weights in pinned VGPRs; x-row via scalar loads
__global__ __launch_bounds__(256)
void k_edge1(const float* __restrict__ x, const int* __restrict__ ei,
             const float* __restrict__ ea, const float* __restrict__ A1,
             const float* __restrict__ b1, float* __restrict__ h1) {
    int lane = threadIdx.x & 63;
    float w0[8], w1[8], bb[8];
#pragma unroll
    for (int i = 0; i < 8; ++i) {
        w0[i] = A1[i * 64 + lane];
        w1[i] = A1[512 + i * 64 + lane];
        bb[i] = b1[i * 64 + lane];
    }
#pragma unroll
    for (int i = 0; i < 8; ++i)
        asm volatile("" : "+v"(w0[i]), "+v"(w1[i]), "+v"(bb[i]));

    int wid = blockIdx.x * (blockDim.x >> 6) + (threadIdx.x >> 6);
    int nw = gridDim.x * (blockDim.x >> 6);
    for (int e = wid; e < N_EDGES; e += nw) {
        int src = __builtin_amdgcn_readfirstlane(ei[e]);
        int dst = __builtin_amdgcn_readfirstlane(ei[N_EDGES + e]);
        float2 eav = ((const float2*)ea)[e];
        float ea0 = rfl_f(eav.x), ea1 = rfl_f(eav.y);
        const float* xp = x + (size_t)src * 8;
        f32x8 h;
        asm volatile("s_load_dwordx8 %0, %1, 0x0\n\t"
                     "s_waitcnt lgkmcnt(0)"
                     : "=s"(h) : "s"(xp));
        float acc = 0.f;
#pragma unroll
        for (int i = 0; i < 8; ++i) {
            float wv = fmaxf(fmaf(ea1, w1[i], fmaf(ea0, w0[i], bb[i])), 0.f);
            acc = fmaf(h[i], wv, acc);
        }
        atomicAdd(&h1[(size_t)dst * 64 + lane], acc);
    }
}

// out[n,o] = bias2[o] + sum_{i<64} h1[n,i] * root2[i,o]
// wave per node; root2 column pinned in VGPRs; h-row via scalar loads
__global__ __launch_bounds__(256)
void k_node2(const float* __restrict__ h1, const float* __restrict__ root2,
             const float* __restrict__ bias2, float* __restrict__ out) {
    int lane = threadIdx.x & 63;
    float r[64];
#pragma unroll
    for (int i = 0; i < 64; ++i) r[i] = root2[i * 64 + lane];
#pragma unroll
    for (int i = 0; i < 64; ++i) asm volatile("" : "+v"(r[i]));
    float bias = bias2[lane];

    int wid = blockIdx.x * (blockDim.x >> 6) + (threadIdx.x >> 6);
    int nw = gridDim.x * (blockDim.x >> 6);
    for (int n = wid; n < N_NODES; n += nw) {
        // n is wave-uniform but LLVM's divergence analysis can't prove it
        // (threadIdx.x >> 6). Launder through readfirstlane so the "s"
        // asm constraint below gets a real SGPR pair.
        int nu = __builtin_amdgcn_readfirstlane(n);
        const float* hp = h1 + (size_t)nu * 64;
        f32x16 h0, h1v, h2, h3;
        asm volatile("s_load_dwordx16 %0, %4, 0x0\n\t"
                     "s_load_dwordx16 %1, %4, 0x40\n\t"
                     "s_load_dwordx16 %2, %4, 0x80\n\t"
                     "s_load_dwordx16 %3, %4, 0xc0\n\t"
                     "s_waitcnt lgkmcnt(0)"
                     : "=s"(h0), "=s"(h1v), "=s"(h2), "=s"(h3) : "s"(hp));
        float acc = bias;
#pragma unroll
        for (int i = 0; i < 16; ++i) acc = fmaf(h0[i],  r[i],      acc);
#pragma unroll
        for (int i = 0; i < 16; ++i) acc = fmaf(h1v[i], r[16 + i], acc);
#pragma unroll
        for (int i = 0; i < 16; ++i) acc = fmaf(h2[i],  r[32 + i], acc);
#pragma unroll
        for (int i = 0; i < 16; ++i) acc = fmaf(h3[i],  r[48 + i], acc);
        out[(size_t)nu * 64 + lane] = acc;
    }
}

// layer-2 edge kernel: wave per edge; 192 weight VGPRs pinned; h-row via scalar loads
__global__ __launch_bounds__(64, 2)
void k_edge2(const float* __restrict__ h1, const int* __restrict__ ei,
             const float* __restrict__ ea, const float* __restrict__ A2,
             const float* __restrict__ b2, float* __restrict__ out) {
    int lane = threadIdx.x;
    float w0[64], w1[64], bb[64];
#pragma unroll
    for (int i = 0; i < 64; ++i) {
        w0[i] = A2[i * 64 + lane];
        w1[i] = A2[4096 + i * 64 + lane];
        bb[i] = b2[i * 64 + lane];
    }
#pragma unroll
    for (int i = 0; i < 64; ++i)
        asm volatile("" : "+v"(w0[i]), "+v"(w1[i]), "+v"(bb[i]));

#pragma clang loop unroll(disable)
    for (int e = blockIdx.x; e < N_EDGES; e += gridDim.x) {
        int src = __builtin_amdgcn_readfirstlane(ei[e]);
        int dst = __builtin_amdgcn_readfirstlane(ei[N_EDGES + e]);
        float2 eav = ((const float2*)ea)[e];
        float ea0 = rfl_f(eav.x), ea1 = rfl_f(eav.y);
        const float* hp = h1 + (size_t)src * 64;
        f32x16 h0, h1v, h2, h3;
        asm volatile("s_load_dwordx16 %0, %4, 0x0\n\t"
                     "s_load_dwordx16 %1, %4, 0x40\n\t"
                     "s_load_dwordx16 %2, %4, 0x80\n\t"
                     "s_load_dwordx16 %3, %4, 0xc0\n\t"
                     "s_waitcnt lgkmcnt(0)"
                     : "=s"(h0), "=s"(h1v), "=s"(h2), "=s"(h3) : "s"(hp));
        float acc = 0.f;
#pragma unroll
        for (int i = 0; i < 16; ++i) {
            float wv = fmaxf(fmaf(ea1, w1[i], fmaf(ea0, w0[i], bb[i])), 0.f);
            acc = fmaf(h0[i], wv, acc);
        }
#pragma unroll
        for (int i = 0; i < 16; ++i) {
            float wv = fmaxf(fmaf(ea1, w1[16 + i], fmaf(ea0, w0[16 + i], bb[16 + i])), 0.f);
            acc = fmaf(h1v[i], wv, acc);
        }
#pragma unroll
        for (int i = 0; i < 16; ++i) {
            float wv = fmaxf(fmaf(ea1, w1[32 + i], fmaf(ea0, w0[32 + i], bb[32 + i])), 0.f);
            acc = fmaf(h2[i], wv, acc);
        }
#pragma unroll
        for (int i = 0; i < 16; ++i) {
            float wv = fmaxf(fmaf(ea1, w1[48 + i], fmaf(ea0, w0[48 + i], bb[48 + i])), 0.f);
            acc = fmaf(h3[i], wv, acc);
        }
        atomicAdd(&out[(size_t)dst * 64 + lane], acc);
    }
}

extern "C" void kernel_launch(void* const* d_in, const int* in_sizes, int n_in,
                              void* d_out, int out_size, void* d_ws, size_t ws_size,
                              hipStream_t stream) {
    const float* x     = (const float*)d_in[0];
    const int*   ei    = (const int*)d_in[1];
    const float* ea    = (const float*)d_in[2];
    const float* A1    = (const float*)d_in[3];
    const float* b1    = (const float*)d_in[4];
    const float* A2    = (const float*)d_in[5];
    const float* b2    = (const float*)d_in[6];
    const float* root1 = (const float*)d_in[7];
    const float* bias1 = (const float*)d_in[8];
    const float* root2 = (const float*)d_in[9];
    const float* bias2 = (const float*)d_in[10];
    float* out = (float*)d_out;
    float* h1  = (float*)d_ws;        // N*64 floats = 4 MB scratch

    // 1) h1 = bias1 + x @ root1   (fully initializes ws accumulator)
    k_node1<<<N_NODES * 64 / 256, 256, 0, stream>>>(x, root1, bias1, h1);
    // 2) h1 += scatter-add of layer-1 edge messages
    k_edge1<<<2048, 256, 0, stream>>>(x, ei, ea, A1, b1, h1);
    // 3) out = bias2 + h1 @ root2 (fully initializes d_out)
    k_node2<<<1024, 256, 0, stream>>>(h1, root2, bias2, out);
    // 4) out += scatter-add of layer-2 edge messages
    k_edge2<<<2048, 64, 0, stream>>>(h1, ei, ea, A2, b2, out);
}

// Round 7
// 142.811 us; speedup vs baseline: 1.3578x; 1.0328x over previous
//
#include <hip/hip_runtime.h>

#define N_NODES 16384
#define N_EDGES 65536

typedef float f32x16 __attribute__((ext_vector_type(16)));
typedef float f32x8  __attribute__((ext_vector_type(8)));

__device__ __forceinline__ float rfl_f(float v) {
    int i = __builtin_amdgcn_readfirstlane(__builtin_bit_cast(int, v));
    return __builtin_bit_cast(float, i);
}

// h1[n,o] = bias1[o] + sum_{i<8} x[n,i] * root1[i,o]
__global__ void k_node1(const float* __restrict__ x, const float* __restrict__ root1,
                        const float* __restrict__ bias1, float* __restrict__ h1) {
    int t = blockIdx.x * blockDim.x + threadIdx.x;   // t in [0, N*64)
    int n = t >> 6, o = t & 63;
    float acc = bias1[o];
#pragma unroll
    for (int i = 0; i < 8; ++i)
        acc = fmaf(x[n * 8 + i], root1[i * 64 + o], acc);
    h1[t] = acc;
}

// layer-1 edge kernel: wave per EDGE-PAIR; 24 weight VGPRs; x-rows via paired scalar loads
__global__ __launch_bounds__(256)
void k_edge1(const float* __restrict__ x, const int* __restrict__ ei,
             const float* __restrict__ ea, const float* __restrict__ A1,
             const float* __restrict__ b1, float* __restrict__ h1) {
    int lane = threadIdx.x & 63;
    float w0[8], w1[8], bb[8];
#pragma unroll
    for (int i = 0; i < 8; ++i) {
        w0[i] = A1[i * 64 + lane];
        w1[i] = A1[512 + i * 64 + lane];
        bb[i] = b1[i * 64 + lane];
    }
#pragma unroll
    for (int i = 0; i < 8; ++i)
        asm volatile("" : "+v"(w0[i]), "+v"(w1[i]), "+v"(bb[i]));

    int wid = blockIdx.x * (blockDim.x >> 6) + (threadIdx.x >> 6);
    int nw = gridDim.x * (blockDim.x >> 6);
#pragma clang loop unroll(disable)
    for (int p = wid; p < N_EDGES / 2; p += nw) {
        int2 srcp = ((const int2*)ei)[p];
        int2 dstp = ((const int2*)(ei + N_EDGES))[p];
        float4 eap = ((const float4*)ea)[p];
        int s0 = __builtin_amdgcn_readfirstlane(srcp.x);
        int s1 = __builtin_amdgcn_readfirstlane(srcp.y);
        int d0 = __builtin_amdgcn_readfirstlane(dstp.x);
        int d1 = __builtin_amdgcn_readfirstlane(dstp.y);
        float ea00 = rfl_f(eap.x), ea01 = rfl_f(eap.y);
        float ea10 = rfl_f(eap.z), ea11 = rfl_f(eap.w);
        const float* xp0 = x + (size_t)s0 * 8;
        const float* xp1 = x + (size_t)s1 * 8;
        f32x8 ha, hb;
        asm volatile("s_load_dwordx8 %0, %2, 0x0\n\t"
                     "s_load_dwordx8 %1, %3, 0x0\n\t"
                     "s_waitcnt lgkmcnt(0)"
                     : "=s"(ha), "=s"(hb) : "s"(xp0), "s"(xp1));
        float acc0 = 0.f, acc1 = 0.f;
#pragma unroll
        for (int i = 0; i < 8; ++i) {
            float wva = fmaxf(fmaf(ea01, w1[i], fmaf(ea00, w0[i], bb[i])), 0.f);
            acc0 = fmaf(ha[i], wva, acc0);
            float wvb = fmaxf(fmaf(ea11, w1[i], fmaf(ea10, w0[i], bb[i])), 0.f);
            acc1 = fmaf(hb[i], wvb, acc1);
        }
        atomicAdd(&h1[(size_t)d0 * 64 + lane], acc0);
        atomicAdd(&h1[(size_t)d1 * 64 + lane], acc1);
    }
}

// out[n,o] = bias2[o] + sum_{i<64} h1[n,i] * root2[i,o]
// wave per node; root2 column pinned in VGPRs; h-row via scalar loads
__global__ __launch_bounds__(256)
void k_node2(const float* __restrict__ h1, const float* __restrict__ root2,
             const float* __restrict__ bias2, float* __restrict__ out) {
    int lane = threadIdx.x & 63;
    float r[64];
#pragma unroll
    for (int i = 0; i < 64; ++i) r[i] = root2[i * 64 + lane];
#pragma unroll
    for (int i = 0; i < 64; ++i) asm volatile("" : "+v"(r[i]));
    float bias = bias2[lane];

    int wid = blockIdx.x * (blockDim.x >> 6) + (threadIdx.x >> 6);
    int nw = gridDim.x * (blockDim.x >> 6);
    for (int n = wid; n < N_NODES; n += nw) {
        // n is wave-uniform but LLVM's divergence analysis can't prove it;
        // launder through readfirstlane so "s" constraints get real SGPRs.
        int nu = __builtin_amdgcn_readfirstlane(n);
        const float* hp = h1 + (size_t)nu * 64;
        f32x16 h0, h1v, h2, h3;
        asm volatile("s_load_dwordx16 %0, %4, 0x0\n\t"
                     "s_load_dwordx16 %1, %4, 0x40\n\t"
                     "s_load_dwordx16 %2, %4, 0x80\n\t"
                     "s_load_dwordx16 %3, %4, 0xc0\n\t"
                     "s_waitcnt lgkmcnt(0)"
                     : "=s"(h0), "=s"(h1v), "=s"(h2), "=s"(h3) : "s"(hp));
        float acc = bias;
#pragma unroll
        for (int i = 0; i < 16; ++i) acc = fmaf(h0[i],  r[i],      acc);
#pragma unroll
        for (int i = 0; i < 16; ++i) acc = fmaf(h1v[i], r[16 + i], acc);
#pragma unroll
        for (int i = 0; i < 16; ++i) acc = fmaf(h2[i],  r[32 + i], acc);
#pragma unroll
        for (int i = 0; i < 16; ++i) acc = fmaf(h3[i],  r[48 + i], acc);
        out[(size_t)nu * 64 + lane] = acc;
    }
}

// layer-2 edge kernel v4: wave handles (edge-pair, i-half).
// Per lane: 32x3 = 96 weight floats -> fits in VGPRs (no AGPR round-trip).
// Two h-half-rows fetched in ONE scalar-load burst (single lgkmcnt stall).
__global__ __launch_bounds__(256)
void k_edge2(const float* __restrict__ h1, const int* __restrict__ ei,
             const float* __restrict__ ea, const float* __restrict__ A2,
             const float* __restrict__ b2, float* __restrict__ out) {
    int lane = threadIdx.x & 63;
    int wid = blockIdx.x * (blockDim.x >> 6) + (threadIdx.x >> 6);
    int nw = gridDim.x * (blockDim.x >> 6);
    // wid is wave-uniform but derived from threadIdx.x>>6, which LLVM's
    // divergence analysis treats as divergent; launder base so pointers
    // built from it satisfy the "s" asm constraints below (R6 fix).
    int base = __builtin_amdgcn_readfirstlane((wid & 1) * 32);

    float w0[32], w1[32], bb[32];
#pragma unroll
    for (int i = 0; i < 32; ++i) {
        int ii = base + i;
        w0[i] = A2[ii * 64 + lane];
        w1[i] = A2[4096 + ii * 64 + lane];
        bb[i] = b2[ii * 64 + lane];
    }
#pragma unroll
    for (int i = 0; i < 32; ++i)
        asm volatile("" : "+v"(w0[i]), "+v"(w1[i]), "+v"(bb[i]));

#pragma clang loop unroll(disable)
    for (int p = wid >> 1; p < N_EDGES / 2; p += (nw >> 1)) {
        int2 srcp = ((const int2*)ei)[p];
        int2 dstp = ((const int2*)(ei + N_EDGES))[p];
        float4 eap = ((const float4*)ea)[p];
        int s0 = __builtin_amdgcn_readfirstlane(srcp.x);
        int s1 = __builtin_amdgcn_readfirstlane(srcp.y);
        int d0 = __builtin_amdgcn_readfirstlane(dstp.x);
        int d1 = __builtin_amdgcn_readfirstlane(dstp.y);
        float ea00 = rfl_f(eap.x), ea01 = rfl_f(eap.y);
        float ea10 = rfl_f(eap.z), ea11 = rfl_f(eap.w);
        const float* hp0 = h1 + (size_t)s0 * 64 + base;   // 32 floats
        const float* hp1 = h1 + (size_t)s1 * 64 + base;
        f32x16 ha, hb, hc, hd;
        asm volatile("s_load_dwordx16 %0, %4, 0x0\n\t"
                     "s_load_dwordx16 %1, %4, 0x40\n\t"
                     "s_load_dwordx16 %2, %5, 0x0\n\t"
                     "s_load_dwordx16 %3, %5, 0x40\n\t"
                     "s_waitcnt lgkmcnt(0)"
                     : "=s"(ha), "=s"(hb), "=s"(hc), "=s"(hd)
                     : "s"(hp0), "s"(hp1));
        float acc0 = 0.f, acc1 = 0.f;
#pragma unroll
        for (int i = 0; i < 16; ++i) {
            float wva = fmaxf(fmaf(ea01, w1[i], fmaf(ea00, w0[i], bb[i])), 0.f);
            acc0 = fmaf(ha[i], wva, acc0);
            float wvb = fmaxf(fmaf(ea11, w1[i], fmaf(ea10, w0[i], bb[i])), 0.f);
            acc1 = fmaf(hc[i], wvb, acc1);
        }
#pragma unroll
        for (int i = 0; i < 16; ++i) {
            float wva = fmaxf(fmaf(ea01, w1[16 + i], fmaf(ea00, w0[16 + i], bb[16 + i])), 0.f);
            acc0 = fmaf(hb[i], wva, acc0);
            float wvb = fmaxf(fmaf(ea11, w1[16 + i], fmaf(ea10, w0[16 + i], bb[16 + i])), 0.f);
            acc1 = fmaf(hd[i], wvb, acc1);
        }
        atomicAdd(&out[(size_t)d0 * 64 + lane], acc0);
        atomicAdd(&out[(size_t)d1 * 64 + lane], acc1);
    }
}

extern "C" void kernel_launch(void* const* d_in, const int* in_sizes, int n_in,
                              void* d_out, int out_size, void* d_ws, size_t ws_size,
                              hipStream_t stream) {
    const float* x     = (const float*)d_in[0];
    const int*   ei    = (const int*)d_in[1];
    const float* ea    = (const float*)d_in[2];
    const float* A1    = (const float*)d_in[3];
    const float* b1    = (const float*)d_in[4];
    const float* A2    = (const float*)d_in[5];
    const float* b2    = (const float*)d_in[6];
    const float* root1 = (const float*)d_in[7];
    const float* bias1 = (const float*)d_in[8];
    const float* root2 = (const float*)d_in[9];
    const float* bias2 = (const float*)d_in[10];
    float* out = (float*)d_out;
    float* h1  = (float*)d_ws;        // N*64 floats = 4 MB scratch

    // 1) h1 = bias1 + x @ root1   (fully initializes ws accumulator)
    k_node1<<<N_NODES * 64 / 256, 256, 0, stream>>>(x, root1, bias1, h1);
    // 2) h1 += scatter-add of layer-1 edge messages
    k_edge1<<<2048, 256, 0, stream>>>(x, ei, ea, A1, b1, h1);
    // 3) out = bias2 + h1 @ root2 (fully initializes d_out)
    k_node2<<<1024, 256, 0, stream>>>(h1, root2, bias2, out);
    // 4) out += scatter-add of layer-2 edge messages
    k_edge2<<<2048, 256, 0, stream>>>(h1, ei, ea, A2, b2, out);
}